// Round 5
// baseline (293.666 us; speedup 1.0000x reference)
//
#include <hip/hip_runtime.h>
#include <math.h>

#define T_STEPS 256
#define BATCH   2048
#define HID     10

// ws layout (floats): z | qmu | qsg | kl | ll   == 16,777,216 floats = 64 MiB
#define ZOFF   0
#define QMUOFF (T_STEPS*BATCH*HID)
#define QSGOFF (2*T_STEPS*BATCH*HID)
#define KLOFF  (3*T_STEPS*BATCH*HID)
#define LLOFF  (KLOFF + T_STEPS*BATCH)

__device__ __forceinline__ float ftanh(float x){ return 1.f - 2.f/(1.f + __expf(2.f*x)); }
__device__ __forceinline__ float fsigm(float x){ return 1.f/(1.f + __expf(-x)); }
__device__ __forceinline__ float frcp (float x){ return __builtin_amdgcn_rcpf(x); }

// DPP row rotate-right by K within each 16-lane row: result[lane j] = src[(j-K)&15]
template<int K> __device__ __forceinline__ float rotk(float x){
  return __int_as_float(__builtin_amdgcn_update_dpp(
      0, __float_as_int(x), 0x120 + K, 0xF, 0xF, false));
}
#define ROT16(r, v) do{ float _v=(v); r[0]=_v; \
  r[1]=rotk<1>(_v);  r[2]=rotk<2>(_v);  r[3]=rotk<3>(_v);  r[4]=rotk<4>(_v);  \
  r[5]=rotk<5>(_v);  r[6]=rotk<6>(_v);  r[7]=rotk<7>(_v);  r[8]=rotk<8>(_v);  \
  r[9]=rotk<9>(_v);  r[10]=rotk<10>(_v);r[11]=rotk<11>(_v);r[12]=rotk<12>(_v);\
  r[13]=rotk<13>(_v);r[14]=rotk<14>(_v);r[15]=rotk<15>(_v); }while(0)

__device__ __forceinline__ float dot16(const float* r, const float* w, float bias){
  float a0 = fmaf(r[0], w[0], bias);
  float a1 = r[1]*w[1];
  float a2 = r[2]*w[2];
  float a3 = r[3]*w[3];
  #pragma unroll
  for (int k=4;k<16;k+=4){
    a0 = fmaf(r[k  ], w[k  ], a0);
    a1 = fmaf(r[k+1], w[k+1], a1);
    a2 = fmaf(r[k+2], w[k+2], a2);
    a3 = fmaf(r[k+3], w[k+3], a3);
  }
  return (a0+a1)+(a2+a3);
}

// dst[k] = W[(j-k)&15][col] if valid else 0  (pre-rotated for rotk order)
template<int NROW, int NCOL>
__device__ __forceinline__ void loadrot(float* dst, const float* W, int j, int col, bool colok){
  int colc = colok ? col : 0;
  #pragma unroll
  for (int k=0;k<16;k++){
    int i = (j - k) & 15;
    bool v = colok && (i < NROW);
    int ic = v ? i : 0;
    float w = W[ic*NCOL + colc];
    dst[k] = v ? w : 0.f;
  }
}
__device__ __forceinline__ float bload(const float* p, int idx, bool ok){
  float t = p[ok ? idx : 0];
  return ok ? t : 0.f;
}
template<int X> __device__ __forceinline__ float xor16(float x){
  return __int_as_float(__builtin_amdgcn_ds_swizzle(__float_as_int(x), (X<<10)|0x1f));
}

// pin a value into a VGPR (opaque redefinition: compiler can't re-load/remat it)
#define PIN1(x)  asm volatile("" : "+v"(x))
#define PIN16(a) do{ _Pragma("unroll") for(int _k=0;_k<16;_k++) PIN1(a[_k]); }while(0)

struct P34 { const float* p[34]; float* ws; float* out; };

// ================= K1: serial inference recurrence (the only sequential part) =================
// waves_per_eu(1,1): tell codegen occupancy is 1 wave/EU no matter what -> allocator has the
// full 512-VGPR budget and zero incentive to spill the pinned weight set.
__global__ __launch_bounds__(64, 1) __attribute__((amdgpu_waves_per_eu(1, 1)))
void k1_recur(P34 prm)
{
  const int tid = threadIdx.x;
  const int j   = tid & 15;
  const int grp = tid >> 4;              // 0..3
  const int b   = blockIdx.x*4 + grp;    // chain id (512 blocks)
  const bool act = (j < HID);
  const int  jl  = act ? j : 0;

  const float* __restrict__ seq   = prm.p[0];
  const float* __restrict__ noise = prm.p[1];
  float* __restrict__ ws = prm.ws;

  // inference weights (live through the loop) — loaded once, PINNED in VGPRs
  float w_ii0   = bload(prm.p[10],      jl, act);
  float w_ii1   = bload(prm.p[10], 10 + jl, act);
  float b_in_in = bload(prm.p[11], jl, act);
  float w_in_j_e[16], w_in_j_z[16], w_in_h[16], w_in_mu[16], w_in_sg[16];
  loadrot<10,10>(w_in_j_e, prm.p[12],       j, j, act);
  loadrot<10,10>(w_in_j_z, prm.p[12] + 100, j, j, act);
  float b_in_j  = bload(prm.p[13], jl, act);
  loadrot<10,10>(w_in_h,  prm.p[14], j, j, act);  float b_in_h  = bload(prm.p[15], jl, act);
  loadrot<10,10>(w_in_mu, prm.p[16], j, j, act);  float b_in_mu = bload(prm.p[17], jl, act);
  loadrot<10,10>(w_in_sg, prm.p[18], j, j, act);  float b_in_sg = bload(prm.p[19], jl, act);
  PIN16(w_in_j_e); PIN16(w_in_j_z); PIN16(w_in_h); PIN16(w_in_mu); PIN16(w_in_sg);
  PIN1(w_ii0); PIN1(w_ii1); PIN1(b_in_in); PIN1(b_in_j); PIN1(b_in_h);
  PIN1(b_in_mu); PIN1(b_in_sg);

  float rz[16];

  auto ldx = [&](int t){ return *reinterpret_cast<const float2*>(seq + t*BATCH*2 + b*2); };
  auto lde = [&](int t){ return noise[t*BATCH*HID + b*HID + jl]; };

  { // t = 0: first_inference (weights die after this scope) + KL vs N(0,1)
    float w0 = bload(prm.p[2],      jl, act);
    float w1 = bload(prm.p[2], 10 + jl, act);
    float bb = bload(prm.p[3], jl, act);
    float w_h[16], w_mu[16], w_sg[16];
    loadrot<10,10>(w_h,  prm.p[4], j, j, act);  float b_h  = bload(prm.p[5], jl, act);
    loadrot<10,10>(w_mu, prm.p[6], j, j, act);  float b_mu = bload(prm.p[7], jl, act);
    loadrot<10,10>(w_sg, prm.p[8], j, j, act);  float b_sg = bload(prm.p[9], jl, act);
    float2 x = ldx(0);
    float eps = lde(0);
    float h0 = ftanh(fmaf(x.x, w0, fmaf(x.y, w1, bb)));
    float r0[16]; ROT16(r0, h0);
    float h1 = ftanh(dot16(r0, w_h, b_h));
    float r1[16]; ROT16(r1, h1);
    float mu = ftanh(dot16(r1, w_mu, b_mu));
    float sg = fsigm(dot16(r1, w_sg, b_sg)) + 0.001f;
    float term = act ? (sg + mu*mu - __logf(sg)) : 0.f;
    term += xor16<1>(term); term += xor16<2>(term); term += xor16<4>(term); term += xor16<8>(term);
    if (j == 0) ws[KLOFF + b] = 0.5f*term;            // kl_half(t=0)
    float z = fmaf(sg, eps, mu);
    if (act){
      ws[ZOFF   + b*HID + jl] = z;
      ws[QMUOFF + b*HID + jl] = mu;
      ws[QSGOFF + b*HID + jl] = sg;
    }
    ROT16(rz, z);
  }

  // 2-deep prefetch of (x, eps)
  float2 xa = ldx(1);            float ea = lde(1);
  float2 xb = ldx(2 < T_STEPS ? 2 : T_STEPS-1);
  float  eb = lde(2 < T_STEPS ? 2 : T_STEPS-1);

  for (int t = 1; t < T_STEPS; ++t){
    float2 x = xa; float eps = ea;
    xa = xb; ea = eb;
    int tn = (t+2 < T_STEPS) ? t+2 : T_STEPS-1;
    xb = ldx(tn); eb = lde(tn);

    float e = ftanh(fmaf(x.x, w_ii0, fmaf(x.y, w_ii1, b_in_in)));
    float re[16]; ROT16(re, e);
    float hj = ftanh(dot16(re, w_in_j_e, b_in_j) + dot16(rz, w_in_j_z, 0.f));
    float rhj[16]; ROT16(rhj, hj);
    float hi = ftanh(dot16(rhj, w_in_h, b_in_h));
    float rhi[16]; ROT16(rhi, hi);
    float q_mu = ftanh(dot16(rhi, w_in_mu, b_in_mu));
    float q_sg = fsigm(dot16(rhi, w_in_sg, b_in_sg)) + 0.001f;
    float z = fmaf(q_sg, eps, q_mu);
    int zW = (t*BATCH + b)*HID + jl;
    if (act){
      ws[ZOFF   + zW] = z;
      ws[QMUOFF + zW] = q_mu;
      ws[QSGOFF + zW] = q_sg;
    }
    ROT16(rz, z);
  }
}

// ================= K2 bodies (parallel over (t,b)) =================
__device__ __forceinline__ void k2_kl_body(const P34& prm, int blk, int tid)
{
  const int j   = tid & 15;
  const int gg  = blk*16 + (tid >> 4);   // 65536 groups
  const bool act = (j < HID);
  const int  jl  = act ? j : 0;
  float* __restrict__ ws = prm.ws;

  float w_h[16], w_mu[16], w_sg[16];
  loadrot<10,10>(w_h,  prm.p[20], j, j, act);  float b_h  = bload(prm.p[21], jl, act);
  loadrot<10,10>(w_mu, prm.p[22], j, j, act);  float b_mu = bload(prm.p[23], jl, act);
  loadrot<10,10>(w_sg, prm.p[24], j, j, act);  float b_sg = bload(prm.p[25], jl, act);

  #pragma unroll 2
  for (int it = 0; it < 8; ++it){
    int i = it*65536 + gg;                      // item over t=1..255, b
    if (i >= (T_STEPS-1)*BATCH) break;
    int t = 1 + (i >> 11);
    int b = i & (BATCH-1);
    int zo = ((t-1)*BATCH + b)*HID + jl;
    int qo = (t*BATCH + b)*HID + jl;
    float zp  = act ? ws[ZOFF   + zo] : 0.f;
    float qmu = act ? ws[QMUOFF + qo] : 0.f;
    float qsg = act ? ws[QSGOFF + qo] : 1.f;
    float rzp[16]; ROT16(rzp, zp);
    float th = ftanh(dot16(rzp, w_h, b_h));
    float rth[16]; ROT16(rth, th);
    float prmu = ftanh(dot16(rth, w_mu, b_mu));
    float prsg = ftanh(dot16(rth, w_sg, b_sg));
    float term = 0.f;
    if (act){
      float dmu = prmu - qmu;
      float rp  = frcp(prsg);
      term = __logf(prsg*frcp(qsg)) + (qsg + dmu*dmu)*rp;
    }
    term += xor16<1>(term); term += xor16<2>(term); term += xor16<4>(term); term += xor16<8>(term);
    if (j == 0) ws[KLOFF + t*BATCH + b] = 0.5f*term;
  }
}

__device__ __forceinline__ void k2_gen_body(const P34& prm, int blk, int tid)
{
  const int j   = tid & 15;
  const int gg  = blk*16 + (tid >> 4);   // 65536 groups
  const bool act = (j < HID);
  const int  jl  = act ? j : 0;
  float* __restrict__ ws = prm.ws;
  const float* __restrict__ seq = prm.p[0];
  float* __restrict__ out = prm.out;

  float w_g1[16], w_g2[16], w_go_mu[16], w_go_sg[16];
  loadrot<10,10>(w_g1, prm.p[26], j, j, act);  float b_g1 = bload(prm.p[27], jl, act);
  loadrot<10,10>(w_g2, prm.p[28], j, j, act);  float b_g2 = bload(prm.p[29], jl, act);
  const bool isd = (j < 2);
  loadrot<10,2>(w_go_mu, prm.p[30], j, j, isd);  float b_go_mu = bload(prm.p[31], j, isd);
  loadrot<10,2>(w_go_sg, prm.p[32], j, j, isd);  float b_go_sg = bload(prm.p[33], j, isd);

  #pragma unroll 2
  for (int it = 0; it < 8; ++it){
    int i = it*65536 + gg;                      // exactly 524288 items
    int t = i >> 11;
    int b = i & (BATCH-1);
    int zo = (t*BATCH + b)*HID + jl;
    float zc = act ? ws[ZOFF + zo] : 0.f;
    float rz[16]; ROT16(rz, zc);
    float g1 = fmaxf(dot16(rz, w_g1, b_g1), 0.f);
    float r1[16]; ROT16(r1, g1);
    float g2 = fmaxf(dot16(r1, w_g2, b_g2), 0.f);
    float r2[16]; ROT16(r2, g2);
    float m = fsigm(dot16(r2, w_go_mu, b_go_mu));
    float s = fsigm(dot16(r2, w_go_sg, b_go_sg));
    float ll = 0.f;
    int go = (t*BATCH + b)*2;
    if (isd){
      float xd = seq[go + j];
      out[go + j] = m;
      float dd = xd - m;
      ll = __logf(s) + dd*dd*frcp(s);
    }
    ll += xor16<1>(ll);
    if (j == 0) ws[LLOFF + t*BATCH + b] = -0.5f*ll;
  }
}

__global__ __launch_bounds__(256, 1) void k2_fused(P34 prm)
{
  if (blockIdx.x < 4096) k2_gen_body(prm, blockIdx.x, threadIdx.x);
  else                   k2_kl_body(prm, blockIdx.x - 4096, threadIdx.x);
}

// ================= K3: loss reduction over t (parallel over t-quarters too) =================
__global__ __launch_bounds__(256, 1) void k3_loss(P34 prm)
{
  __shared__ float red[256];
  const int tid = threadIdx.x;
  const int bl  = tid & 63;
  const int q   = tid >> 6;                      // t-quarter
  const int b   = blockIdx.x*64 + bl;            // grid 32 -> 2048
  const float* __restrict__ kl = prm.ws + KLOFF;
  const float* __restrict__ ll = prm.ws + LLOFF;
  float s = 0.f;
  #pragma unroll 4
  for (int tt = 0; tt < 64; ++tt){
    int t = q*64 + tt;
    s += kl[t*BATCH + b] + ll[t*BATCH + b];
  }
  red[tid] = s;
  __syncthreads();
  if (q == 0){
    s = red[bl] + red[bl+64] + red[bl+128] + red[bl+192];
    const float LOGPI = 1.1447298858494002f;
    prm.out[T_STEPS*BATCH*2 + b] = -s*(1.0f/(float)T_STEPS) + 5.0f + LOGPI;
  }
}

extern "C" void kernel_launch(void* const* d_in, const int* in_sizes, int n_in,
                              void* d_out, int out_size, void* d_ws, size_t ws_size,
                              hipStream_t stream) {
  P34 prm;
  for (int i = 0; i < 34; ++i) prm.p[i] = (const float*)d_in[i];
  prm.ws  = (float*)d_ws;      // needs 64 MiB
  prm.out = (float*)d_out;
  hipLaunchKernelGGL(k1_recur, dim3(512),  dim3(64),  0, stream, prm);
  hipLaunchKernelGGL(k2_fused, dim3(8192), dim3(256), 0, stream, prm);
  hipLaunchKernelGGL(k3_loss,  dim3(32),   dim3(256), 0, stream, prm);
}

// Round 6
// 268.556 us; speedup vs baseline: 1.0935x; 1.0935x over previous
//
#include <hip/hip_runtime.h>
#include <math.h>

#define T_STEPS 256
#define BATCH   2048
#define HID     10

// ws layout (floats): z | qmu | qsg | kl | ll   == 16,777,216 floats = 64 MiB
#define ZOFF   0
#define QMUOFF (T_STEPS*BATCH*HID)
#define QSGOFF (2*T_STEPS*BATCH*HID)
#define KLOFF  (3*T_STEPS*BATCH*HID)
#define LLOFF  (KLOFF + T_STEPS*BATCH)

__device__ __forceinline__ float frcp (float x){ return __builtin_amdgcn_rcpf(x); }
// division-free activations: v_exp_f32 + v_rcp_f32 only (no div_scale/div_fixup chains)
__device__ __forceinline__ float ftanh(float x){ return 1.f - 2.f*frcp(1.f + __expf(2.f*x)); }
__device__ __forceinline__ float fsigm(float x){ return frcp(1.f + __expf(-x)); }

// DPP row rotate-right by K within each 16-lane row: result[lane j] = src[(j-K)&15]
template<int K> __device__ __forceinline__ float rotk(float x){
  return __int_as_float(__builtin_amdgcn_update_dpp(
      0, __float_as_int(x), 0x120 + K, 0xF, 0xF, false));
}
#define ROT16(r, v) do{ float _v=(v); r[0]=_v; \
  r[1]=rotk<1>(_v);  r[2]=rotk<2>(_v);  r[3]=rotk<3>(_v);  r[4]=rotk<4>(_v);  \
  r[5]=rotk<5>(_v);  r[6]=rotk<6>(_v);  r[7]=rotk<7>(_v);  r[8]=rotk<8>(_v);  \
  r[9]=rotk<9>(_v);  r[10]=rotk<10>(_v);r[11]=rotk<11>(_v);r[12]=rotk<12>(_v);\
  r[13]=rotk<13>(_v);r[14]=rotk<14>(_v);r[15]=rotk<15>(_v); }while(0)

__device__ __forceinline__ float dot16(const float* r, const float* w, float bias){
  float a0 = fmaf(r[0], w[0], bias);
  float a1 = r[1]*w[1];
  float a2 = r[2]*w[2];
  float a3 = r[3]*w[3];
  #pragma unroll
  for (int k=4;k<16;k+=4){
    a0 = fmaf(r[k  ], w[k  ], a0);
    a1 = fmaf(r[k+1], w[k+1], a1);
    a2 = fmaf(r[k+2], w[k+2], a2);
    a3 = fmaf(r[k+3], w[k+3], a3);
  }
  return (a0+a1)+(a2+a3);
}

// dst[k] = W[(j-k)&15][col] if valid else 0  (pre-rotated for rotk order)
template<int NROW, int NCOL>
__device__ __forceinline__ void loadrot(float* dst, const float* W, int j, int col, bool colok){
  int colc = colok ? col : 0;
  #pragma unroll
  for (int k=0;k<16;k++){
    int i = (j - k) & 15;
    bool v = colok && (i < NROW);
    int ic = v ? i : 0;
    float w = W[ic*NCOL + colc];
    dst[k] = v ? w : 0.f;
  }
}
__device__ __forceinline__ float bload(const float* p, int idx, bool ok){
  float t = p[ok ? idx : 0];
  return ok ? t : 0.f;
}
template<int X> __device__ __forceinline__ float xor16(float x){
  return __int_as_float(__builtin_amdgcn_ds_swizzle(__float_as_int(x), (X<<10)|0x1f));
}

struct P34 { const float* p[34]; float* ws; float* out; };

// ================= K1: serial inference recurrence (the only sequential part) =================
// waves_per_eu(1,1): occupancy target = 1 wave/EU -> full 512-VGPR budget, allocator has no
// incentive to spill the loop-invariant weight set. (No __launch_bounds__ — it would inject a
// second, conflicting waves-per-eu minimum.)
__global__ __attribute__((amdgpu_flat_work_group_size(64, 64), amdgpu_waves_per_eu(1, 1)))
void k1_recur(P34 prm)
{
  const int tid = threadIdx.x;
  const int j   = tid & 15;
  const int grp = tid >> 4;              // 0..3
  const int b   = blockIdx.x*4 + grp;    // chain id (512 blocks)
  const bool act = (j < HID);
  const int  jl  = act ? j : 0;

  const float* __restrict__ seq   = prm.p[0];
  const float* __restrict__ noise = prm.p[1];
  float* __restrict__ ws = prm.ws;

  // inference weights (live through the loop) — loaded once, should stay VGPR-resident
  float w_ii0   = bload(prm.p[10],      jl, act);
  float w_ii1   = bload(prm.p[10], 10 + jl, act);
  float b_in_in = bload(prm.p[11], jl, act);
  float w_in_j_e[16], w_in_j_z[16], w_in_h[16], w_in_mu[16], w_in_sg[16];
  loadrot<10,10>(w_in_j_e, prm.p[12],       j, j, act);
  loadrot<10,10>(w_in_j_z, prm.p[12] + 100, j, j, act);
  float b_in_j  = bload(prm.p[13], jl, act);
  loadrot<10,10>(w_in_h,  prm.p[14], j, j, act);  float b_in_h  = bload(prm.p[15], jl, act);
  loadrot<10,10>(w_in_mu, prm.p[16], j, j, act);  float b_in_mu = bload(prm.p[17], jl, act);
  loadrot<10,10>(w_in_sg, prm.p[18], j, j, act);  float b_in_sg = bload(prm.p[19], jl, act);

  float rz[16];

  auto ldx = [&](int t){ return *reinterpret_cast<const float2*>(seq + t*BATCH*2 + b*2); };
  auto lde = [&](int t){ return noise[t*BATCH*HID + b*HID + jl]; };

  { // t = 0: first_inference (weights die after this scope) + KL vs N(0,1)
    float w0 = bload(prm.p[2],      jl, act);
    float w1 = bload(prm.p[2], 10 + jl, act);
    float bb = bload(prm.p[3], jl, act);
    float w_h[16], w_mu[16], w_sg[16];
    loadrot<10,10>(w_h,  prm.p[4], j, j, act);  float b_h  = bload(prm.p[5], jl, act);
    loadrot<10,10>(w_mu, prm.p[6], j, j, act);  float b_mu = bload(prm.p[7], jl, act);
    loadrot<10,10>(w_sg, prm.p[8], j, j, act);  float b_sg = bload(prm.p[9], jl, act);
    float2 x = ldx(0);
    float eps = lde(0);
    float h0 = ftanh(fmaf(x.x, w0, fmaf(x.y, w1, bb)));
    float r0[16]; ROT16(r0, h0);
    float h1 = ftanh(dot16(r0, w_h, b_h));
    float r1[16]; ROT16(r1, h1);
    float mu = ftanh(dot16(r1, w_mu, b_mu));
    float sg = fsigm(dot16(r1, w_sg, b_sg)) + 0.001f;
    float term = act ? (sg + mu*mu - __logf(sg)) : 0.f;
    term += xor16<1>(term); term += xor16<2>(term); term += xor16<4>(term); term += xor16<8>(term);
    if (j == 0) ws[KLOFF + b] = 0.5f*term;            // kl_half(t=0)
    float z = fmaf(sg, eps, mu);
    if (act){
      ws[ZOFF   + b*HID + jl] = z;
      ws[QMUOFF + b*HID + jl] = mu;
      ws[QSGOFF + b*HID + jl] = sg;
    }
    ROT16(rz, z);
  }

  // 2-deep prefetch of (x, eps)
  float2 xa = ldx(1);            float ea = lde(1);
  float2 xb = ldx(2 < T_STEPS ? 2 : T_STEPS-1);
  float  eb = lde(2 < T_STEPS ? 2 : T_STEPS-1);

  for (int t = 1; t < T_STEPS; ++t){
    float2 x = xa; float eps = ea;
    xa = xb; ea = eb;
    int tn = (t+2 < T_STEPS) ? t+2 : T_STEPS-1;
    xb = ldx(tn); eb = lde(tn);

    float e = ftanh(fmaf(x.x, w_ii0, fmaf(x.y, w_ii1, b_in_in)));
    float re[16]; ROT16(re, e);
    float hj = ftanh(dot16(re, w_in_j_e, b_in_j) + dot16(rz, w_in_j_z, 0.f));
    float rhj[16]; ROT16(rhj, hj);
    float hi = ftanh(dot16(rhj, w_in_h, b_in_h));
    float rhi[16]; ROT16(rhi, hi);
    float q_mu = ftanh(dot16(rhi, w_in_mu, b_in_mu));
    float q_sg = fsigm(dot16(rhi, w_in_sg, b_in_sg)) + 0.001f;
    float z = fmaf(q_sg, eps, q_mu);
    int zW = (t*BATCH + b)*HID + jl;
    if (act){
      ws[ZOFF   + zW] = z;
      ws[QMUOFF + zW] = q_mu;
      ws[QSGOFF + zW] = q_sg;
    }
    ROT16(rz, z);
  }
}

// ================= K2 bodies (parallel over (t,b)) =================
__device__ __forceinline__ void k2_kl_body(const P34& prm, int blk, int tid)
{
  const int j   = tid & 15;
  const int gg  = blk*16 + (tid >> 4);   // 65536 groups
  const bool act = (j < HID);
  const int  jl  = act ? j : 0;
  float* __restrict__ ws = prm.ws;

  float w_h[16], w_mu[16], w_sg[16];
  loadrot<10,10>(w_h,  prm.p[20], j, j, act);  float b_h  = bload(prm.p[21], jl, act);
  loadrot<10,10>(w_mu, prm.p[22], j, j, act);  float b_mu = bload(prm.p[23], jl, act);
  loadrot<10,10>(w_sg, prm.p[24], j, j, act);  float b_sg = bload(prm.p[25], jl, act);

  #pragma unroll 2
  for (int it = 0; it < 8; ++it){
    int i = it*65536 + gg;                      // item over t=1..255, b
    if (i >= (T_STEPS-1)*BATCH) break;
    int t = 1 + (i >> 11);
    int b = i & (BATCH-1);
    int zo = ((t-1)*BATCH + b)*HID + jl;
    int qo = (t*BATCH + b)*HID + jl;
    float zp  = act ? ws[ZOFF   + zo] : 0.f;
    float qmu = act ? ws[QMUOFF + qo] : 0.f;
    float qsg = act ? ws[QSGOFF + qo] : 1.f;
    float rzp[16]; ROT16(rzp, zp);
    float th = ftanh(dot16(rzp, w_h, b_h));
    float rth[16]; ROT16(rth, th);
    float prmu = ftanh(dot16(rth, w_mu, b_mu));
    float prsg = ftanh(dot16(rth, w_sg, b_sg));
    float term = 0.f;
    if (act){
      float dmu = prmu - qmu;
      float rp  = frcp(prsg);
      term = __logf(prsg*frcp(qsg)) + (qsg + dmu*dmu)*rp;
    }
    term += xor16<1>(term); term += xor16<2>(term); term += xor16<4>(term); term += xor16<8>(term);
    if (j == 0) ws[KLOFF + t*BATCH + b] = 0.5f*term;
  }
}

__device__ __forceinline__ void k2_gen_body(const P34& prm, int blk, int tid)
{
  const int j   = tid & 15;
  const int gg  = blk*16 + (tid >> 4);   // 65536 groups
  const bool act = (j < HID);
  const int  jl  = act ? j : 0;
  float* __restrict__ ws = prm.ws;
  const float* __restrict__ seq = prm.p[0];
  float* __restrict__ out = prm.out;

  float w_g1[16], w_g2[16], w_go_mu[16], w_go_sg[16];
  loadrot<10,10>(w_g1, prm.p[26], j, j, act);  float b_g1 = bload(prm.p[27], jl, act);
  loadrot<10,10>(w_g2, prm.p[28], j, j, act);  float b_g2 = bload(prm.p[29], jl, act);
  const bool isd = (j < 2);
  loadrot<10,2>(w_go_mu, prm.p[30], j, j, isd);  float b_go_mu = bload(prm.p[31], j, isd);
  loadrot<10,2>(w_go_sg, prm.p[32], j, j, isd);  float b_go_sg = bload(prm.p[33], j, isd);

  #pragma unroll 2
  for (int it = 0; it < 8; ++it){
    int i = it*65536 + gg;                      // exactly 524288 items
    int t = i >> 11;
    int b = i & (BATCH-1);
    int zo = (t*BATCH + b)*HID + jl;
    float zc = act ? ws[ZOFF + zo] : 0.f;
    float rz[16]; ROT16(rz, zc);
    float g1 = fmaxf(dot16(rz, w_g1, b_g1), 0.f);
    float r1[16]; ROT16(r1, g1);
    float g2 = fmaxf(dot16(r1, w_g2, b_g2), 0.f);
    float r2[16]; ROT16(r2, g2);
    float m = fsigm(dot16(r2, w_go_mu, b_go_mu));
    float s = fsigm(dot16(r2, w_go_sg, b_go_sg));
    float ll = 0.f;
    int go = (t*BATCH + b)*2;
    if (isd){
      float xd = seq[go + j];
      out[go + j] = m;
      float dd = xd - m;
      ll = __logf(s) + dd*dd*frcp(s);
    }
    ll += xor16<1>(ll);
    if (j == 0) ws[LLOFF + t*BATCH + b] = -0.5f*ll;
  }
}

__global__ __launch_bounds__(256, 1) void k2_fused(P34 prm)
{
  if (blockIdx.x < 4096) k2_gen_body(prm, blockIdx.x, threadIdx.x);
  else                   k2_kl_body(prm, blockIdx.x - 4096, threadIdx.x);
}

// ================= K3: loss reduction over t (parallel over t-quarters too) =================
__global__ __launch_bounds__(256, 1) void k3_loss(P34 prm)
{
  __shared__ float red[256];
  const int tid = threadIdx.x;
  const int bl  = tid & 63;
  const int q   = tid >> 6;                      // t-quarter
  const int b   = blockIdx.x*64 + bl;            // grid 32 -> 2048
  const float* __restrict__ kl = prm.ws + KLOFF;
  const float* __restrict__ ll = prm.ws + LLOFF;
  float s = 0.f;
  #pragma unroll 4
  for (int tt = 0; tt < 64; ++tt){
    int t = q*64 + tt;
    s += kl[t*BATCH + b] + ll[t*BATCH + b];
  }
  red[tid] = s;
  __syncthreads();
  if (q == 0){
    s = red[bl] + red[bl+64] + red[bl+128] + red[bl+192];
    const float LOGPI = 1.1447298858494002f;
    prm.out[T_STEPS*BATCH*2 + b] = -s*(1.0f/(float)T_STEPS) + 5.0f + LOGPI;
  }
}

extern "C" void kernel_launch(void* const* d_in, const int* in_sizes, int n_in,
                              void* d_out, int out_size, void* d_ws, size_t ws_size,
                              hipStream_t stream) {
  P34 prm;
  for (int i = 0; i < 34; ++i) prm.p[i] = (const float*)d_in[i];
  prm.ws  = (float*)d_ws;      // needs 64 MiB
  prm.out = (float*)d_out;
  hipLaunchKernelGGL(k1_recur, dim3(512),  dim3(64),  0, stream, prm);
  hipLaunchKernelGGL(k2_fused, dim3(8192), dim3(256), 0, stream, prm);
  hipLaunchKernelGGL(k3_loss,  dim3(32),   dim3(256), 0, stream, prm);
}

// Round 7
// 194.174 us; speedup vs baseline: 1.5124x; 1.3831x over previous
//
#include <hip/hip_runtime.h>
#include <math.h>

#define T_STEPS 256
#define BATCH   2048
#define HID     10

// ws layout (floats): z | qmu | qsg | kl | ll   == 16,777,216 floats = 64 MiB
#define ZOFF   0
#define QMUOFF (T_STEPS*BATCH*HID)
#define QSGOFF (2*T_STEPS*BATCH*HID)
#define KLOFF  (3*T_STEPS*BATCH*HID)
#define LLOFF  (KLOFF + T_STEPS*BATCH)

#define S2P  2.8853900817779268f   // 2/ln2
#define SNP -1.4426950408889634f   // -1/ln2

__device__ __forceinline__ float frcp(float x){ return __builtin_amdgcn_rcpf(x); }
__device__ __forceinline__ float ex2 (float x){ return __builtin_amdgcn_exp2f(x); }
// pre-scaled activations: input already multiplied by 2/ln2 (tanh) or -1/ln2 (sigm)
__device__ __forceinline__ float ftanh2(float y){ return 1.f - 2.f*frcp(1.f + ex2(y)); }
__device__ __forceinline__ float fsigm2(float y){ return frcp(1.f + ex2(y)); }
// unscaled-input versions (for lane-per-item kernels)
__device__ __forceinline__ float ftanhU(float x){ return ftanh2(S2P*x); }
__device__ __forceinline__ float fsigmU(float x){ return fsigm2(SNP*x); }

// DPP row rotate-right by K within each 16-lane row: result[lane j] = src[(j-K)&15]
template<int K> __device__ __forceinline__ float rotk(float x){
  return __int_as_float(__builtin_amdgcn_update_dpp(
      0, __float_as_int(x), 0x120 + K, 0xF, 0xF, false));
}
#define ROT16(r, v) do{ float _v=(v); r[0]=_v; \
  r[1]=rotk<1>(_v);  r[2]=rotk<2>(_v);  r[3]=rotk<3>(_v);  r[4]=rotk<4>(_v);  \
  r[5]=rotk<5>(_v);  r[6]=rotk<6>(_v);  r[7]=rotk<7>(_v);  r[8]=rotk<8>(_v);  \
  r[9]=rotk<9>(_v);  r[10]=rotk<10>(_v);r[11]=rotk<11>(_v);r[12]=rotk<12>(_v);\
  r[13]=rotk<13>(_v);r[14]=rotk<14>(_v);r[15]=rotk<15>(_v); }while(0)

__device__ __forceinline__ float dot16(const float* r, const float* w, float bias){
  float a0 = fmaf(r[0], w[0], bias);
  float a1 = r[1]*w[1];
  float a2 = r[2]*w[2];
  float a3 = r[3]*w[3];
  #pragma unroll
  for (int k=4;k<16;k+=4){
    a0 = fmaf(r[k  ], w[k  ], a0);
    a1 = fmaf(r[k+1], w[k+1], a1);
    a2 = fmaf(r[k+2], w[k+2], a2);
    a3 = fmaf(r[k+3], w[k+3], a3);
  }
  return (a0+a1)+(a2+a3);
}

// dst[k] = scale * W[(j-k)&15][col] if valid else 0  (pre-rotated for rotk order)
template<int NROW, int NCOL>
__device__ __forceinline__ void loadrot(float* dst, const float* W, int j, int col,
                                        bool colok, float scale){
  int colc = colok ? col : 0;
  #pragma unroll
  for (int k=0;k<16;k++){
    int i = (j - k) & 15;
    bool v = colok && (i < NROW);
    int ic = v ? i : 0;
    float w = W[ic*NCOL + colc];
    dst[k] = v ? scale*w : 0.f;
  }
}
__device__ __forceinline__ float bload(const float* p, int idx, bool ok, float scale){
  float t = p[ok ? idx : 0];
  return ok ? scale*t : 0.f;
}
template<int X> __device__ __forceinline__ float xor16(float x){
  return __int_as_float(__builtin_amdgcn_ds_swizzle(__float_as_int(x), (X<<10)|0x1f));
}

struct P34 { const float* p[34]; float* ws; float* out; };

// ================= K1: serial inference recurrence (3-stage chain, e-stage pipelined) =========
__global__ __attribute__((amdgpu_flat_work_group_size(64, 64), amdgpu_waves_per_eu(1, 1)))
void k1_recur(P34 prm)
{
  const int tid = threadIdx.x;
  const int j   = tid & 15;
  const int grp = tid >> 4;              // 0..3
  const int b   = blockIdx.x*4 + grp;    // chain id (512 blocks)
  const bool act = (j < HID);
  const int  jl  = act ? j : 0;

  const float* __restrict__ seq   = prm.p[0];
  const float* __restrict__ noise = prm.p[1];
  float* __restrict__ ws = prm.ws;

  // inference weights, pre-scaled for direct exp2 activations
  float w_ii0   = bload(prm.p[10],      jl, act, S2P);
  float w_ii1   = bload(prm.p[10], 10 + jl, act, S2P);
  float b_in_in = bload(prm.p[11], jl, act, S2P);
  float w_je[16], w_jz[16], w_h[16], w_mu[16], w_sg[16];
  loadrot<10,10>(w_je, prm.p[12],       j, j, act, S2P);
  loadrot<10,10>(w_jz, prm.p[12] + 100, j, j, act, S2P);
  float b_in_j  = bload(prm.p[13], jl, act, S2P);
  loadrot<10,10>(w_h,  prm.p[14], j, j, act, S2P);  float b_in_h  = bload(prm.p[15], jl, act, S2P);
  loadrot<10,10>(w_mu, prm.p[16], j, j, act, S2P);  float b_in_mu = bload(prm.p[17], jl, act, S2P);
  loadrot<10,10>(w_sg, prm.p[18], j, j, act, SNP);  float b_in_sg = bload(prm.p[19], jl, act, SNP);

  float rz[16];

  auto ldx = [&](int t){ return *reinterpret_cast<const float2*>(seq + t*BATCH*2 + b*2); };
  auto lde = [&](int t){ return noise[t*BATCH*HID + b*HID + jl]; };

  { // t = 0: first_inference (one-time weights) + KL vs N(0,1)
    float w0 = bload(prm.p[2],      jl, act, S2P);
    float w1 = bload(prm.p[2], 10 + jl, act, S2P);
    float bb = bload(prm.p[3], jl, act, S2P);
    float f_h[16], f_mu[16], f_sg[16];
    loadrot<10,10>(f_h,  prm.p[4], j, j, act, S2P);  float fb_h  = bload(prm.p[5], jl, act, S2P);
    loadrot<10,10>(f_mu, prm.p[6], j, j, act, S2P);  float fb_mu = bload(prm.p[7], jl, act, S2P);
    loadrot<10,10>(f_sg, prm.p[8], j, j, act, SNP);  float fb_sg = bload(prm.p[9], jl, act, SNP);
    float2 x = ldx(0);
    float eps = lde(0);
    float h0 = ftanh2(fmaf(x.x, w0, fmaf(x.y, w1, bb)));
    float r0[16]; ROT16(r0, h0);
    float h1 = ftanh2(dot16(r0, f_h, fb_h));
    float r1[16]; ROT16(r1, h1);
    float mu = ftanh2(dot16(r1, f_mu, fb_mu));
    float sg = fsigm2(dot16(r1, f_sg, fb_sg)) + 0.001f;
    float term = act ? (sg + mu*mu - __logf(sg)) : 0.f;
    term += xor16<1>(term); term += xor16<2>(term); term += xor16<4>(term); term += xor16<8>(term);
    if (j == 0) ws[KLOFF + b] = 0.5f*term;            // kl_half(t=0)
    float z = fmaf(sg, eps, mu);
    if (act){
      ws[ZOFF   + b*HID + jl] = z;
      ws[QMUOFF + b*HID + jl] = mu;
      ws[QSGOFF + b*HID + jl] = sg;
    }
    ROT16(rz, z);
  }

  // pipeline prologue: ae for t=1; x for t=2; eps 2-deep
  float ae_c;
  {
    float2 x1 = ldx(1);
    float e1 = ftanh2(fmaf(x1.x, w_ii0, fmaf(x1.y, w_ii1, b_in_in)));
    float re1[16]; ROT16(re1, e1);
    ae_c = dot16(re1, w_je, b_in_j);
  }
  float2 xa = ldx(2);
  float  ec = lde(1);
  float  en = lde(2);

  for (int t = 1; t < T_STEPS; ++t){
    int t2 = (t+2 < T_STEPS) ? t+2 : T_STEPS-1;
    float2 xb = ldx(t2);
    float  ef = lde(t2);

    // independent work: ae(t+1) from xa — fills the chain's stall slots
    float e = ftanh2(fmaf(xa.x, w_ii0, fmaf(xa.y, w_ii1, b_in_in)));
    float re[16]; ROT16(re, e);
    float ae_n = dot16(re, w_je, b_in_j);

    // serial chain: hj -> hi -> (mu,sg) -> z
    float hj = ftanh2(ae_c + dot16(rz, w_jz, 0.f));
    float rhj[16]; ROT16(rhj, hj);
    float hi = ftanh2(dot16(rhj, w_h, b_in_h));
    float rhi[16]; ROT16(rhi, hi);
    float q_mu = ftanh2(dot16(rhi, w_mu, b_in_mu));
    float q_sg = fsigm2(dot16(rhi, w_sg, b_in_sg)) + 0.001f;
    float z = fmaf(q_sg, ec, q_mu);
    int zW = (t*BATCH + b)*HID + jl;
    if (act){
      ws[ZOFF   + zW] = z;
      ws[QMUOFF + zW] = q_mu;
      ws[QSGOFF + zW] = q_sg;
    }
    ROT16(rz, z);

    ae_c = ae_n; xa = xb; ec = en; en = ef;
  }
}

// ================= K2-gen: lane-per-item generator + GLL (524288 items) =================
__global__ __attribute__((amdgpu_flat_work_group_size(256, 256), amdgpu_waves_per_eu(1, 1)))
void k2_gen(P34 prm)
{
  const int i = blockIdx.x*256 + threadIdx.x;     // = t*BATCH + b
  float* __restrict__ ws = prm.ws;
  const float* __restrict__ seq = prm.p[0];
  float* __restrict__ out = prm.out;

  // uniform weights (broadcast loads)
  float w1[100], b1[10], w2[100], b2[10], wm[20], bm[2], wsg[20], bs[2];
  #pragma unroll
  for (int k=0;k<100;k++) w1[k] = prm.p[26][k];
  #pragma unroll
  for (int k=0;k<10;k++)  b1[k] = prm.p[27][k];
  #pragma unroll
  for (int k=0;k<100;k++) w2[k] = prm.p[28][k];
  #pragma unroll
  for (int k=0;k<10;k++)  b2[k] = prm.p[29][k];
  #pragma unroll
  for (int k=0;k<20;k++)  wm[k] = prm.p[30][k];
  #pragma unroll
  for (int k=0;k<2;k++)   bm[k] = prm.p[31][k];
  #pragma unroll
  for (int k=0;k<20;k++)  wsg[k]= prm.p[32][k];
  #pragma unroll
  for (int k=0;k<2;k++)   bs[k] = prm.p[33][k];

  // z[i][0..9] (10-packed, 8B-aligned)
  const float* zp = ws + ZOFF + i*10;
  float z[10];
  #pragma unroll
  for (int k=0;k<5;k++){ float2 v = *reinterpret_cast<const float2*>(zp + 2*k); z[2*k]=v.x; z[2*k+1]=v.y; }

  float h1[10];
  #pragma unroll
  for (int o=0;o<10;o++){
    float a = b1[o];
    #pragma unroll
    for (int k=0;k<10;k++) a = fmaf(z[k], w1[k*10+o], a);
    h1[o] = fmaxf(a, 0.f);
  }
  float h2[10];
  #pragma unroll
  for (int o=0;o<10;o++){
    float a = b2[o];
    #pragma unroll
    for (int k=0;k<10;k++) a = fmaf(h1[k], w2[k*10+o], a);
    h2[o] = fmaxf(a, 0.f);
  }
  float m0,m1,s0,s1;
  {
    float am0=bm[0], am1=bm[1], as0=bs[0], as1=bs[1];
    #pragma unroll
    for (int k=0;k<10;k++){
      am0 = fmaf(h2[k], wm[k*2+0], am0);
      am1 = fmaf(h2[k], wm[k*2+1], am1);
      as0 = fmaf(h2[k], wsg[k*2+0], as0);
      as1 = fmaf(h2[k], wsg[k*2+1], as1);
    }
    m0=fsigmU(am0); m1=fsigmU(am1); s0=fsigmU(as0); s1=fsigmU(as1);
  }
  float2 xv = *reinterpret_cast<const float2*>(seq + i*2);
  float d0 = xv.x - m0, d1 = xv.y - m1;
  float ll = __logf(s0) + __logf(s1) + d0*d0*frcp(s0) + d1*d1*frcp(s1);
  float2 mo; mo.x = m0; mo.y = m1;
  *reinterpret_cast<float2*>(out + i*2) = mo;
  ws[LLOFF + i] = -0.5f*ll;
}

// ================= K2-kl: lane-per-item transition + KLD (522240 items, t=1..255) ============
__global__ __attribute__((amdgpu_flat_work_group_size(256, 256), amdgpu_waves_per_eu(1, 1)))
void k2_kl(P34 prm)
{
  const int i = blockIdx.x*256 + threadIdx.x;     // 0..522239
  const int t = 1 + (i >> 11);
  const int b = i & (BATCH-1);
  float* __restrict__ ws = prm.ws;

  float wh[100], bh[10], wmu[100], bmu[10], wsg[100], bsg[10];
  #pragma unroll
  for (int k=0;k<100;k++) wh[k]  = prm.p[20][k];
  #pragma unroll
  for (int k=0;k<10;k++)  bh[k]  = prm.p[21][k];
  #pragma unroll
  for (int k=0;k<100;k++) wmu[k] = prm.p[22][k];
  #pragma unroll
  for (int k=0;k<10;k++)  bmu[k] = prm.p[23][k];
  #pragma unroll
  for (int k=0;k<100;k++) wsg[k] = prm.p[24][k];
  #pragma unroll
  for (int k=0;k<10;k++)  bsg[k] = prm.p[25][k];

  const float* zp  = ws + ZOFF   + ((t-1)*BATCH + b)*10;
  const float* qmp = ws + QMUOFF + (t*BATCH + b)*10;
  const float* qsp = ws + QSGOFF + (t*BATCH + b)*10;
  float z[10], qmu[10], qsg[10];
  #pragma unroll
  for (int k=0;k<5;k++){
    float2 v;
    v = *reinterpret_cast<const float2*>(zp  + 2*k); z[2*k]=v.x;   z[2*k+1]=v.y;
    v = *reinterpret_cast<const float2*>(qmp + 2*k); qmu[2*k]=v.x; qmu[2*k+1]=v.y;
    v = *reinterpret_cast<const float2*>(qsp + 2*k); qsg[2*k]=v.x; qsg[2*k+1]=v.y;
  }

  float th[10];
  #pragma unroll
  for (int o=0;o<10;o++){
    float a = bh[o];
    #pragma unroll
    for (int k=0;k<10;k++) a = fmaf(z[k], wh[k*10+o], a);
    th[o] = ftanhU(a);
  }
  float kl = 0.f;
  #pragma unroll
  for (int o=0;o<10;o++){
    float am = bmu[o], as = bsg[o];
    #pragma unroll
    for (int k=0;k<10;k++){
      am = fmaf(th[k], wmu[k*10+o], am);
      as = fmaf(th[k], wsg[k*10+o], as);
    }
    float prmu = ftanhU(am);
    float prsg = ftanhU(as);
    float dmu = prmu - qmu[o];
    float rp  = frcp(prsg);
    kl += __logf(prsg*frcp(qsg[o])) + (qsg[o] + dmu*dmu)*rp;
  }
  ws[KLOFF + t*BATCH + b] = 0.5f*kl;
}

// ================= K3: loss reduction over t =================
__global__ __launch_bounds__(256, 1) void k3_loss(P34 prm)
{
  __shared__ float red[256];
  const int tid = threadIdx.x;
  const int bl  = tid & 63;
  const int q   = tid >> 6;                      // t-quarter
  const int b   = blockIdx.x*64 + bl;            // grid 32 -> 2048
  const float* __restrict__ kl = prm.ws + KLOFF;
  const float* __restrict__ ll = prm.ws + LLOFF;
  float s = 0.f;
  #pragma unroll 4
  for (int tt = 0; tt < 64; ++tt){
    int t = q*64 + tt;
    s += kl[t*BATCH + b] + ll[t*BATCH + b];
  }
  red[tid] = s;
  __syncthreads();
  if (q == 0){
    s = red[bl] + red[bl+64] + red[bl+128] + red[bl+192];
    const float LOGPI = 1.1447298858494002f;
    prm.out[T_STEPS*BATCH*2 + b] = -s*(1.0f/(float)T_STEPS) + 5.0f + LOGPI;
  }
}

extern "C" void kernel_launch(void* const* d_in, const int* in_sizes, int n_in,
                              void* d_out, int out_size, void* d_ws, size_t ws_size,
                              hipStream_t stream) {
  P34 prm;
  for (int i = 0; i < 34; ++i) prm.p[i] = (const float*)d_in[i];
  prm.ws  = (float*)d_ws;      // needs 64 MiB
  prm.out = (float*)d_out;
  hipLaunchKernelGGL(k1_recur, dim3(512),  dim3(64),  0, stream, prm);
  hipLaunchKernelGGL(k2_gen,   dim3(2048), dim3(256), 0, stream, prm);
  hipLaunchKernelGGL(k2_kl,    dim3(2040), dim3(256), 0, stream, prm);
  hipLaunchKernelGGL(k3_loss,  dim3(32),   dim3(256), 0, stream, prm);
}

// Round 8
// 186.059 us; speedup vs baseline: 1.5784x; 1.0436x over previous
//
#include <hip/hip_runtime.h>
#include <math.h>

#define T_STEPS 256
#define BATCH   2048
#define HID     10

// ws layout (floats): z | qmu | qsg | kl | ll   == 16,777,216 floats = 64 MiB
#define ZOFF   0
#define QMUOFF (T_STEPS*BATCH*HID)
#define QSGOFF (2*T_STEPS*BATCH*HID)
#define KLOFF  (3*T_STEPS*BATCH*HID)
#define LLOFF  (KLOFF + T_STEPS*BATCH)

#define S2P  2.8853900817779268f   // 2/ln2
#define SNP -1.4426950408889634f   // -1/ln2

__device__ __forceinline__ float frcp(float x){ return __builtin_amdgcn_rcpf(x); }
__device__ __forceinline__ float ex2 (float x){ return __builtin_amdgcn_exp2f(x); }
// pre-scaled activations: input already multiplied by 2/ln2 (tanh) or -1/ln2 (sigm)
__device__ __forceinline__ float ftanh2(float y){ return 1.f - 2.f*frcp(1.f + ex2(y)); }
__device__ __forceinline__ float fsigm2(float y){ return frcp(1.f + ex2(y)); }
// unscaled-input versions (for lane-per-item kernels)
__device__ __forceinline__ float ftanhU(float x){ return ftanh2(S2P*x); }
__device__ __forceinline__ float fsigmU(float x){ return fsigm2(SNP*x); }

// DPP row rotate-right by K within each 16-lane row: result[lane j] = src[(j-K)&15]
template<int K> __device__ __forceinline__ float rotk(float x){
  return __int_as_float(__builtin_amdgcn_update_dpp(
      0, __float_as_int(x), 0x120 + K, 0xF, 0xF, false));
}
#define ROT16(r, v) do{ float _v=(v); r[0]=_v; \
  r[1]=rotk<1>(_v);  r[2]=rotk<2>(_v);  r[3]=rotk<3>(_v);  r[4]=rotk<4>(_v);  \
  r[5]=rotk<5>(_v);  r[6]=rotk<6>(_v);  r[7]=rotk<7>(_v);  r[8]=rotk<8>(_v);  \
  r[9]=rotk<9>(_v);  r[10]=rotk<10>(_v);r[11]=rotk<11>(_v);r[12]=rotk<12>(_v);\
  r[13]=rotk<13>(_v);r[14]=rotk<14>(_v);r[15]=rotk<15>(_v); }while(0)

__device__ __forceinline__ float dot16(const float* r, const float* w, float bias){
  float a0 = fmaf(r[0], w[0], bias);
  float a1 = r[1]*w[1];
  float a2 = r[2]*w[2];
  float a3 = r[3]*w[3];
  #pragma unroll
  for (int k=4;k<16;k+=4){
    a0 = fmaf(r[k  ], w[k  ], a0);
    a1 = fmaf(r[k+1], w[k+1], a1);
    a2 = fmaf(r[k+2], w[k+2], a2);
    a3 = fmaf(r[k+3], w[k+3], a3);
  }
  return (a0+a1)+(a2+a3);
}

// dst[k] = scale * W[(j-k)&15][col] if valid else 0  (pre-rotated for rotk order)
template<int NROW, int NCOL>
__device__ __forceinline__ void loadrot(float* dst, const float* W, int j, int col,
                                        bool colok, float scale){
  int colc = colok ? col : 0;
  #pragma unroll
  for (int k=0;k<16;k++){
    int i = (j - k) & 15;
    bool v = colok && (i < NROW);
    int ic = v ? i : 0;
    float w = W[ic*NCOL + colc];
    dst[k] = v ? scale*w : 0.f;
  }
}
__device__ __forceinline__ float bload(const float* p, int idx, bool ok, float scale){
  float t = p[ok ? idx : 0];
  return ok ? scale*t : 0.f;
}
template<int X> __device__ __forceinline__ float xor16(float x){
  return __int_as_float(__builtin_amdgcn_ds_swizzle(__float_as_int(x), (X<<10)|0x1f));
}
__device__ __forceinline__ int imin(int a, int b){ return a<b?a:b; }

struct P34 { const float* p[34]; float* ws; float* out; };

// ================= K1: serial inference recurrence (blocked 4-step prefetch) =================
__global__ __attribute__((amdgpu_flat_work_group_size(64, 64), amdgpu_waves_per_eu(1, 1)))
void k1_recur(P34 prm)
{
  const int tid = threadIdx.x;
  const int j   = tid & 15;
  const int grp = tid >> 4;              // 0..3
  const int b   = blockIdx.x*4 + grp;    // chain id (512 blocks)
  const bool act = (j < HID);
  const int  jl  = act ? j : 0;

  const float* __restrict__ seq   = prm.p[0];
  const float* __restrict__ noise = prm.p[1];
  float* __restrict__ ws = prm.ws;

  // inference weights, pre-scaled for direct exp2 activations
  float w_ii0   = bload(prm.p[10],      jl, act, S2P);
  float w_ii1   = bload(prm.p[10], 10 + jl, act, S2P);
  float b_in_in = bload(prm.p[11], jl, act, S2P);
  float w_je[16], w_jz[16], w_h[16], w_mu[16], w_sg[16];
  loadrot<10,10>(w_je, prm.p[12],       j, j, act, S2P);
  loadrot<10,10>(w_jz, prm.p[12] + 100, j, j, act, S2P);
  float b_in_j  = bload(prm.p[13], jl, act, S2P);
  loadrot<10,10>(w_h,  prm.p[14], j, j, act, S2P);  float b_in_h  = bload(prm.p[15], jl, act, S2P);
  loadrot<10,10>(w_mu, prm.p[16], j, j, act, S2P);  float b_in_mu = bload(prm.p[17], jl, act, S2P);
  loadrot<10,10>(w_sg, prm.p[18], j, j, act, SNP);  float b_in_sg = bload(prm.p[19], jl, act, SNP);

  float rz[16];

  auto ldx = [&](int t){ return *reinterpret_cast<const float2*>(seq + t*BATCH*2 + b*2); };
  auto lde = [&](int t){ return noise[t*BATCH*HID + b*HID + jl]; };

  { // t = 0: first_inference (one-time weights) + KL vs N(0,1)
    float w0 = bload(prm.p[2],      jl, act, S2P);
    float w1 = bload(prm.p[2], 10 + jl, act, S2P);
    float bb = bload(prm.p[3], jl, act, S2P);
    float f_h[16], f_mu[16], f_sg[16];
    loadrot<10,10>(f_h,  prm.p[4], j, j, act, S2P);  float fb_h  = bload(prm.p[5], jl, act, S2P);
    loadrot<10,10>(f_mu, prm.p[6], j, j, act, S2P);  float fb_mu = bload(prm.p[7], jl, act, S2P);
    loadrot<10,10>(f_sg, prm.p[8], j, j, act, SNP);  float fb_sg = bload(prm.p[9], jl, act, SNP);
    float2 x = ldx(0);
    float eps = lde(0);
    float h0 = ftanh2(fmaf(x.x, w0, fmaf(x.y, w1, bb)));
    float r0[16]; ROT16(r0, h0);
    float h1 = ftanh2(dot16(r0, f_h, fb_h));
    float r1[16]; ROT16(r1, h1);
    float mu = ftanh2(dot16(r1, f_mu, fb_mu));
    float sg = fsigm2(dot16(r1, f_sg, fb_sg)) + 0.001f;
    float term = act ? (sg + mu*mu - __logf(sg)) : 0.f;
    term += xor16<1>(term); term += xor16<2>(term); term += xor16<4>(term); term += xor16<8>(term);
    if (j == 0) ws[KLOFF + b] = 0.5f*term;            // kl_half(t=0)
    float z = fmaf(sg, eps, mu);
    if (act){
      ws[ZOFF   + b*HID + jl] = z;
      ws[QMUOFF + b*HID + jl] = mu;
      ws[QSGOFF + b*HID + jl] = sg;
    }
    ROT16(rz, z);
  }

  // pipeline prologue: ae for t=1 from x(1)
  float ae_c;
  {
    float2 x1 = ldx(1);
    float e1 = ftanh2(fmaf(x1.x, w_ii0, fmaf(x1.y, w_ii1, b_in_in)));
    float re1[16]; ROT16(re1, e1);
    ae_c = dot16(re1, w_je, b_in_j);
  }

  // block-0 buffers: steps 1..4 need x(2..5), eps(1..4)
  float2 xq0=ldx(2), xq1=ldx(3), xq2=ldx(4), xq3=ldx(5);
  float  eq0=lde(1), eq1=lde(2), eq2=lde(3), eq3=lde(4);

  for (int bt = 0; bt < 64; ++bt){
    const int base = 4*bt;             // this block: steps base+1 .. base+4
    const int nb   = base + 4;         // next block: steps nb+1 .. nb+4
    // issue next block's 8 loads up-front; they drain while this block computes
    float2 xn0=ldx(imin(nb+2,255)), xn1=ldx(imin(nb+3,255)),
           xn2=ldx(imin(nb+4,255)), xn3=ldx(imin(nb+5,255));
    float  en0=lde(imin(nb+1,255)), en1=lde(imin(nb+2,255)),
           en2=lde(imin(nb+3,255)), en3=lde(imin(nb+4,255));

    #pragma unroll
    for (int k = 0; k < 4; ++k){
      const int t = base + 1 + k;
      if (t > 255) break;              // uniform; only triggers in last block
      float2 xa = (k==0)?xq0:(k==1)?xq1:(k==2)?xq2:xq3;   // x(t+1)
      float  ec = (k==0)?eq0:(k==1)?eq1:(k==2)?eq2:eq3;   // eps(t)

      // independent work: ae(t+1) — fills the chain's stall slots
      float e = ftanh2(fmaf(xa.x, w_ii0, fmaf(xa.y, w_ii1, b_in_in)));
      float re[16]; ROT16(re, e);
      float ae_n = dot16(re, w_je, b_in_j);

      // serial chain: hj -> hi -> (mu,sg) -> z
      float hj = ftanh2(ae_c + dot16(rz, w_jz, 0.f));
      float rhj[16]; ROT16(rhj, hj);
      float hi = ftanh2(dot16(rhj, w_h, b_in_h));
      float rhi[16]; ROT16(rhi, hi);
      float q_mu = ftanh2(dot16(rhi, w_mu, b_in_mu));
      float q_sg = fsigm2(dot16(rhi, w_sg, b_in_sg)) + 0.001f;
      float z = fmaf(q_sg, ec, q_mu);
      int zW = (t*BATCH + b)*HID + jl;
      if (act){
        ws[ZOFF   + zW] = z;
        ws[QMUOFF + zW] = q_mu;
        ws[QSGOFF + zW] = q_sg;
      }
      ROT16(rz, z);
      ae_c = ae_n;
    }
    xq0=xn0; xq1=xn1; xq2=xn2; xq3=xn3;
    eq0=en0; eq1=en1; eq2=en2; eq3=en3;
  }
}

// ================= K2-gen: lane-per-item generator + GLL (524288 items) =================
__global__ __attribute__((amdgpu_flat_work_group_size(256, 256), amdgpu_waves_per_eu(1, 1)))
void k2_gen(P34 prm)
{
  const int i = blockIdx.x*256 + threadIdx.x;     // = t*BATCH + b
  float* __restrict__ ws = prm.ws;
  const float* __restrict__ seq = prm.p[0];
  float* __restrict__ out = prm.out;

  // uniform weights (broadcast loads)
  float w1[100], b1[10], w2[100], b2[10], wm[20], bm[2], wsg[20], bs[2];
  #pragma unroll
  for (int k=0;k<100;k++) w1[k] = prm.p[26][k];
  #pragma unroll
  for (int k=0;k<10;k++)  b1[k] = prm.p[27][k];
  #pragma unroll
  for (int k=0;k<100;k++) w2[k] = prm.p[28][k];
  #pragma unroll
  for (int k=0;k<10;k++)  b2[k] = prm.p[29][k];
  #pragma unroll
  for (int k=0;k<20;k++)  wm[k] = prm.p[30][k];
  #pragma unroll
  for (int k=0;k<2;k++)   bm[k] = prm.p[31][k];
  #pragma unroll
  for (int k=0;k<20;k++)  wsg[k]= prm.p[32][k];
  #pragma unroll
  for (int k=0;k<2;k++)   bs[k] = prm.p[33][k];

  // z[i][0..9] (10-packed, 8B-aligned)
  const float* zp = ws + ZOFF + i*10;
  float z[10];
  #pragma unroll
  for (int k=0;k<5;k++){ float2 v = *reinterpret_cast<const float2*>(zp + 2*k); z[2*k]=v.x; z[2*k+1]=v.y; }

  float h1[10];
  #pragma unroll
  for (int o=0;o<10;o++){
    float a = b1[o];
    #pragma unroll
    for (int k=0;k<10;k++) a = fmaf(z[k], w1[k*10+o], a);
    h1[o] = fmaxf(a, 0.f);
  }
  float h2[10];
  #pragma unroll
  for (int o=0;o<10;o++){
    float a = b2[o];
    #pragma unroll
    for (int k=0;k<10;k++) a = fmaf(h1[k], w2[k*10+o], a);
    h2[o] = fmaxf(a, 0.f);
  }
  float m0,m1,s0,s1;
  {
    float am0=bm[0], am1=bm[1], as0=bs[0], as1=bs[1];
    #pragma unroll
    for (int k=0;k<10;k++){
      am0 = fmaf(h2[k], wm[k*2+0], am0);
      am1 = fmaf(h2[k], wm[k*2+1], am1);
      as0 = fmaf(h2[k], wsg[k*2+0], as0);
      as1 = fmaf(h2[k], wsg[k*2+1], as1);
    }
    m0=fsigmU(am0); m1=fsigmU(am1); s0=fsigmU(as0); s1=fsigmU(as1);
  }
  float2 xv = *reinterpret_cast<const float2*>(seq + i*2);
  float d0 = xv.x - m0, d1 = xv.y - m1;
  float ll = __logf(s0) + __logf(s1) + d0*d0*frcp(s0) + d1*d1*frcp(s1);
  float2 mo; mo.x = m0; mo.y = m1;
  *reinterpret_cast<float2*>(out + i*2) = mo;
  ws[LLOFF + i] = -0.5f*ll;
}

// ================= K2-kl: lane-per-item transition + KLD (522240 items, t=1..255) ============
__global__ __attribute__((amdgpu_flat_work_group_size(256, 256), amdgpu_waves_per_eu(1, 1)))
void k2_kl(P34 prm)
{
  const int i = blockIdx.x*256 + threadIdx.x;     // 0..522239
  const int t = 1 + (i >> 11);
  const int b = i & (BATCH-1);
  float* __restrict__ ws = prm.ws;

  float wh[100], bh[10], wmu[100], bmu[10], wsg[100], bsg[10];
  #pragma unroll
  for (int k=0;k<100;k++) wh[k]  = prm.p[20][k];
  #pragma unroll
  for (int k=0;k<10;k++)  bh[k]  = prm.p[21][k];
  #pragma unroll
  for (int k=0;k<100;k++) wmu[k] = prm.p[22][k];
  #pragma unroll
  for (int k=0;k<10;k++)  bmu[k] = prm.p[23][k];
  #pragma unroll
  for (int k=0;k<100;k++) wsg[k] = prm.p[24][k];
  #pragma unroll
  for (int k=0;k<10;k++)  bsg[k] = prm.p[25][k];

  const float* zp  = ws + ZOFF   + ((t-1)*BATCH + b)*10;
  const float* qmp = ws + QMUOFF + (t*BATCH + b)*10;
  const float* qsp = ws + QSGOFF + (t*BATCH + b)*10;
  float z[10], qmu[10], qsg[10];
  #pragma unroll
  for (int k=0;k<5;k++){
    float2 v;
    v = *reinterpret_cast<const float2*>(zp  + 2*k); z[2*k]=v.x;   z[2*k+1]=v.y;
    v = *reinterpret_cast<const float2*>(qmp + 2*k); qmu[2*k]=v.x; qmu[2*k+1]=v.y;
    v = *reinterpret_cast<const float2*>(qsp + 2*k); qsg[2*k]=v.x; qsg[2*k+1]=v.y;
  }

  float th[10];
  #pragma unroll
  for (int o=0;o<10;o++){
    float a = bh[o];
    #pragma unroll
    for (int k=0;k<10;k++) a = fmaf(z[k], wh[k*10+o], a);
    th[o] = ftanhU(a);
  }
  float kl = 0.f;
  #pragma unroll
  for (int o=0;o<10;o++){
    float am = bmu[o], as = bsg[o];
    #pragma unroll
    for (int k=0;k<10;k++){
      am = fmaf(th[k], wmu[k*10+o], am);
      as = fmaf(th[k], wsg[k*10+o], as);
    }
    float prmu = ftanhU(am);
    float prsg = ftanhU(as);
    float dmu = prmu - qmu[o];
    float rp  = frcp(prsg);
    kl += __logf(prsg*frcp(qsg[o])) + (qsg[o] + dmu*dmu)*rp;
  }
  ws[KLOFF + t*BATCH + b] = 0.5f*kl;
}

// ================= K3: loss reduction over t =================
__global__ __launch_bounds__(256, 1) void k3_loss(P34 prm)
{
  __shared__ float red[256];
  const int tid = threadIdx.x;
  const int bl  = tid & 63;
  const int q   = tid >> 6;                      // t-quarter
  const int b   = blockIdx.x*64 + bl;            // grid 32 -> 2048
  const float* __restrict__ kl = prm.ws + KLOFF;
  const float* __restrict__ ll = prm.ws + LLOFF;
  float s = 0.f;
  #pragma unroll 4
  for (int tt = 0; tt < 64; ++tt){
    int t = q*64 + tt;
    s += kl[t*BATCH + b] + ll[t*BATCH + b];
  }
  red[tid] = s;
  __syncthreads();
  if (q == 0){
    s = red[bl] + red[bl+64] + red[bl+128] + red[bl+192];
    const float LOGPI = 1.1447298858494002f;
    prm.out[T_STEPS*BATCH*2 + b] = -s*(1.0f/(float)T_STEPS) + 5.0f + LOGPI;
  }
}

extern "C" void kernel_launch(void* const* d_in, const int* in_sizes, int n_in,
                              void* d_out, int out_size, void* d_ws, size_t ws_size,
                              hipStream_t stream) {
  P34 prm;
  for (int i = 0; i < 34; ++i) prm.p[i] = (const float*)d_in[i];
  prm.ws  = (float*)d_ws;      // needs 64 MiB
  prm.out = (float*)d_out;
  hipLaunchKernelGGL(k1_recur, dim3(512),  dim3(64),  0, stream, prm);
  hipLaunchKernelGGL(k2_gen,   dim3(2048), dim3(256), 0, stream, prm);
  hipLaunchKernelGGL(k2_kl,    dim3(2040), dim3(256), 0, stream, prm);
  hipLaunchKernelGGL(k3_loss,  dim3(32),   dim3(256), 0, stream, prm);
}

// Round 9
// 173.824 us; speedup vs baseline: 1.6894x; 1.0704x over previous
//
#include <hip/hip_runtime.h>
#include <math.h>

#define T_STEPS 256
#define BATCH   2048
#define HID     10

// ws layout (floats): z | qmu | qsg | kl | ll   == 16,777,216 floats = 64 MiB
#define ZOFF   0
#define QMUOFF (T_STEPS*BATCH*HID)
#define QSGOFF (2*T_STEPS*BATCH*HID)
#define KLOFF  (3*T_STEPS*BATCH*HID)
#define LLOFF  (KLOFF + T_STEPS*BATCH)

#define S2P  2.8853900817779268f   // 2/ln2
#define SNP -1.4426950408889634f   // -1/ln2

typedef float v2f __attribute__((ext_vector_type(2)));

__device__ __forceinline__ float frcp(float x){ return __builtin_amdgcn_rcpf(x); }
__device__ __forceinline__ float ex2 (float x){ return __builtin_amdgcn_exp2f(x); }
__device__ __forceinline__ float ftanh2(float y){ return 1.f - 2.f*frcp(1.f + ex2(y)); }
__device__ __forceinline__ float fsigm2(float y){ return frcp(1.f + ex2(y)); }
__device__ __forceinline__ float ftanhU(float x){ return ftanh2(S2P*x); }
__device__ __forceinline__ float fsigmU(float x){ return fsigm2(SNP*x); }

// DPP row rotate-right by K within each 16-lane row: result[lane j] = src[(j-K)&15]
template<int K> __device__ __forceinline__ float rotk(float x){
  return __int_as_float(__builtin_amdgcn_update_dpp(
      0, __float_as_int(x), 0x120 + K, 0xF, 0xF, false));
}
#define ROT16(r, v) do{ float _v=(v); r[0]=_v; \
  r[1]=rotk<1>(_v);  r[2]=rotk<2>(_v);  r[3]=rotk<3>(_v);  r[4]=rotk<4>(_v);  \
  r[5]=rotk<5>(_v);  r[6]=rotk<6>(_v);  r[7]=rotk<7>(_v);  r[8]=rotk<8>(_v);  \
  r[9]=rotk<9>(_v);  r[10]=rotk<10>(_v);r[11]=rotk<11>(_v);r[12]=rotk<12>(_v);\
  r[13]=rotk<13>(_v);r[14]=rotk<14>(_v);r[15]=rotk<15>(_v); }while(0)

// rotate a PAIR {a,b} together: r[k] = { a<-rot k, b<-rot k }  (30 DPPs, pre-paired for pk_fma)
#define ROTP(r, a, b) do{ float _a=(a), _b=(b); r[0]=(v2f){_a,_b}; \
  r[1]=(v2f){rotk<1>(_a),rotk<1>(_b)};   r[2]=(v2f){rotk<2>(_a),rotk<2>(_b)}; \
  r[3]=(v2f){rotk<3>(_a),rotk<3>(_b)};   r[4]=(v2f){rotk<4>(_a),rotk<4>(_b)}; \
  r[5]=(v2f){rotk<5>(_a),rotk<5>(_b)};   r[6]=(v2f){rotk<6>(_a),rotk<6>(_b)}; \
  r[7]=(v2f){rotk<7>(_a),rotk<7>(_b)};   r[8]=(v2f){rotk<8>(_a),rotk<8>(_b)}; \
  r[9]=(v2f){rotk<9>(_a),rotk<9>(_b)};   r[10]=(v2f){rotk<10>(_a),rotk<10>(_b)}; \
  r[11]=(v2f){rotk<11>(_a),rotk<11>(_b)};r[12]=(v2f){rotk<12>(_a),rotk<12>(_b)}; \
  r[13]=(v2f){rotk<13>(_a),rotk<13>(_b)};r[14]=(v2f){rotk<14>(_a),rotk<14>(_b)}; \
  r[15]=(v2f){rotk<15>(_a),rotk<15>(_b)}; }while(0)

__device__ __forceinline__ float dot16(const float* r, const float* w, float bias){
  float a0 = fmaf(r[0], w[0], bias);
  float a1 = r[1]*w[1];
  float a2 = r[2]*w[2];
  float a3 = r[3]*w[3];
  #pragma unroll
  for (int k=4;k<16;k+=4){
    a0 = fmaf(r[k  ], w[k  ], a0);
    a1 = fmaf(r[k+1], w[k+1], a1);
    a2 = fmaf(r[k+2], w[k+2], a2);
    a3 = fmaf(r[k+3], w[k+3], a3);
  }
  return (a0+a1)+(a2+a3);
}

// two dots at once via v_pk_fma_f32 (4-way split accumulators)
__device__ __forceinline__ v2f dotp16(const v2f* r, const v2f* w, v2f init){
  v2f a0 = __builtin_elementwise_fma(r[0], w[0], init);
  v2f a1 = r[1]*w[1];
  v2f a2 = r[2]*w[2];
  v2f a3 = r[3]*w[3];
  #pragma unroll
  for (int k=4;k<16;k+=4){
    a0 = __builtin_elementwise_fma(r[k  ], w[k  ], a0);
    a1 = __builtin_elementwise_fma(r[k+1], w[k+1], a1);
    a2 = __builtin_elementwise_fma(r[k+2], w[k+2], a2);
    a3 = __builtin_elementwise_fma(r[k+3], w[k+3], a3);
  }
  return (a0+a1)+(a2+a3);
}

// scalar dot against the .x halves of packed weights
__device__ __forceinline__ float dot16x(const float* r, const v2f* w, float bias){
  float a0 = fmaf(r[0], w[0].x, bias);
  float a1 = r[1]*w[1].x;
  float a2 = r[2]*w[2].x;
  float a3 = r[3]*w[3].x;
  #pragma unroll
  for (int k=4;k<16;k+=4){
    a0 = fmaf(r[k  ], w[k  ].x, a0);
    a1 = fmaf(r[k+1], w[k+1].x, a1);
    a2 = fmaf(r[k+2], w[k+2].x, a2);
    a3 = fmaf(r[k+3], w[k+3].x, a3);
  }
  return (a0+a1)+(a2+a3);
}

// dst[k] = scale * W[(j-k)&15][col] if valid else 0  (pre-rotated for rotk order)
template<int NROW, int NCOL>
__device__ __forceinline__ void loadrot(float* dst, const float* W, int j, int col,
                                        bool colok, float scale){
  int colc = colok ? col : 0;
  #pragma unroll
  for (int k=0;k<16;k++){
    int i = (j - k) & 15;
    bool v = colok && (i < NROW);
    int ic = v ? i : 0;
    float w = W[ic*NCOL + colc];
    dst[k] = v ? scale*w : 0.f;
  }
}
__device__ __forceinline__ float bload(const float* p, int idx, bool ok, float scale){
  float t = p[ok ? idx : 0];
  return ok ? scale*t : 0.f;
}
template<int X> __device__ __forceinline__ float xor16(float x){
  return __int_as_float(__builtin_amdgcn_ds_swizzle(__float_as_int(x), (X<<10)|0x1f));
}

struct P34 { const float* p[34]; float* ws; float* out; };

// ================= K1: serial inference recurrence (packed math, blocked prefetch) ============
__global__ __attribute__((amdgpu_flat_work_group_size(64, 64), amdgpu_waves_per_eu(1, 1)))
void k1_recur(P34 prm)
{
  const int tid = threadIdx.x;
  const int j   = tid & 15;
  const int grp = tid >> 4;              // 0..3
  const int b   = blockIdx.x*4 + grp;    // chain id (512 blocks)
  const bool act = (j < HID);
  const int  jl  = act ? j : 0;

  const float* __restrict__ seq   = prm.p[0];
  const float* __restrict__ noise = prm.p[1];
  float* __restrict__ ws = prm.ws;

  // packed loop weights: wez[k] = {w_je, w_jz} ; wmsg[k] = {w_mu(S2P), w_sg(SNP)}
  float w_ii0   = bload(prm.p[10],      jl, act, S2P);
  float w_ii1   = bload(prm.p[10], 10 + jl, act, S2P);
  float b_in_in = bload(prm.p[11], jl, act, S2P);
  float tje[16], tjz[16], tmu[16], tsg[16], w_h[16];
  loadrot<10,10>(tje, prm.p[12],       j, j, act, S2P);
  loadrot<10,10>(tjz, prm.p[12] + 100, j, j, act, S2P);
  loadrot<10,10>(w_h, prm.p[14],       j, j, act, S2P);
  loadrot<10,10>(tmu, prm.p[16],       j, j, act, S2P);
  loadrot<10,10>(tsg, prm.p[18],       j, j, act, SNP);
  v2f wez[16], wmsg[16];
  #pragma unroll
  for (int k=0;k<16;k++){ wez[k]=(v2f){tje[k],tjz[k]}; wmsg[k]=(v2f){tmu[k],tsg[k]}; }
  float b_in_j  = bload(prm.p[13], jl, act, S2P);
  float b_in_h  = bload(prm.p[15], jl, act, S2P);
  float b_in_mu = bload(prm.p[17], jl, act, S2P);
  float b_in_sg = bload(prm.p[19], jl, act, SNP);
  const v2f bmsg = (v2f){b_in_mu, b_in_sg};

  auto ldx = [&](int t){ return *reinterpret_cast<const float2*>(seq + t*BATCH*2 + b*2); };
  auto lde = [&](int t){ return noise[t*BATCH*HID + b*HID + jl]; };

  float z_prev;     // scalar latent (lane j holds z[j])
  float ae_c;       // pipelined e-contribution for current step (bias included)

  { // t = 0: first_inference (one-time weights) + KL vs N(0,1)
    float w0 = bload(prm.p[2],      jl, act, S2P);
    float w1 = bload(prm.p[2], 10 + jl, act, S2P);
    float bb = bload(prm.p[3], jl, act, S2P);
    float f_h[16], f_mu[16], f_sg[16];
    loadrot<10,10>(f_h,  prm.p[4], j, j, act, S2P);  float fb_h  = bload(prm.p[5], jl, act, S2P);
    loadrot<10,10>(f_mu, prm.p[6], j, j, act, S2P);  float fb_mu = bload(prm.p[7], jl, act, S2P);
    loadrot<10,10>(f_sg, prm.p[8], j, j, act, SNP);  float fb_sg = bload(prm.p[9], jl, act, SNP);
    float2 x = ldx(0);
    float eps = lde(0);
    float h0 = ftanh2(fmaf(x.x, w0, fmaf(x.y, w1, bb)));
    float r0[16]; ROT16(r0, h0);
    float h1 = ftanh2(dot16(r0, f_h, fb_h));
    float r1[16]; ROT16(r1, h1);
    float mu = ftanh2(dot16(r1, f_mu, fb_mu));
    float sg = fsigm2(dot16(r1, f_sg, fb_sg)) + 0.001f;
    float term = act ? (sg + mu*mu - __logf(sg)) : 0.f;
    term += xor16<1>(term); term += xor16<2>(term); term += xor16<4>(term); term += xor16<8>(term);
    if (j == 0) ws[KLOFF + b] = 0.5f*term;
    float z = fmaf(sg, eps, mu);
    if (act){
      ws[ZOFF   + b*HID + jl] = z;
      ws[QMUOFF + b*HID + jl] = mu;
      ws[QSGOFF + b*HID + jl] = sg;
    }
    z_prev = z;
  }

  { // pipeline prologue: ae for t=1 from x(1)
    float2 x1 = ldx(1);
    float e1 = ftanh2(fmaf(x1.x, w_ii0, fmaf(x1.y, w_ii1, b_in_in)));
    float re1[16]; ROT16(re1, e1);
    ae_c = dot16x(re1, wez, b_in_j);
  }

  // one step: consumes xa = x(t+1), ec = eps(t); updates z_prev, ae_c
  auto step = [&](int t, float2 xa, float ec){
    float e = ftanh2(fmaf(xa.x, w_ii0, fmaf(xa.y, w_ii1, b_in_in)));
    v2f rez[16]; ROTP(rez, e, z_prev);                 // {e-rot, z-rot} pre-paired
    v2f d1 = dotp16(rez, wez, (v2f){b_in_j, 0.f});     // {ae(t+1), z-contrib}
    float hj = ftanh2(ae_c + d1.y);
    float rhj[16]; ROT16(rhj, hj);
    float hi = ftanh2(dot16(rhj, w_h, b_in_h));
    float rhi[16]; ROT16(rhi, hi);
    v2f hh[16];
    #pragma unroll
    for (int k=0;k<16;k++) hh[k] = (v2f){rhi[k], rhi[k]};
    v2f d2 = dotp16(hh, wmsg, bmsg);                   // {mu-pre, sg-pre}
    float q_mu = ftanh2(d2.x);
    float q_sg = fsigm2(d2.y) + 0.001f;
    float z = fmaf(q_sg, ec, q_mu);
    int zW = (t*BATCH + b)*HID + jl;
    if (act){
      ws[ZOFF   + zW] = z;
      ws[QMUOFF + zW] = q_mu;
      ws[QSGOFF + zW] = q_sg;
    }
    z_prev = z;
    ae_c = d1.x;
  };

  // block-0 buffers: steps 1..4 need x(2..5), eps(1..4)
  float2 xq0=ldx(2), xq1=ldx(3), xq2=ldx(4), xq3=ldx(5);
  float  eq0=lde(1), eq1=lde(2), eq2=lde(3), eq3=lde(4);

  // main: bt=0..61 -> steps 1..248, all prefetch indices in range (no clamps -> LSR-friendly)
  for (int bt = 0; bt < 62; ++bt){
    const int base = 4*bt;
    float2 xn0=ldx(base+6), xn1=ldx(base+7), xn2=ldx(base+8), xn3=ldx(base+9);
    float  en0=lde(base+5), en1=lde(base+6), en2=lde(base+7), en3=lde(base+8);
    step(base+1, xq0, eq0);
    step(base+2, xq1, eq1);
    step(base+3, xq2, eq2);
    step(base+4, xq3, eq3);
    xq0=xn0; xq1=xn1; xq2=xn2; xq3=xn3;
    eq0=en0; eq1=en1; eq2=en2; eq3=en3;
  }
  // tail: queues now hold x(250..253), eps(249..252)
  step(249, xq0, eq0);
  step(250, xq1, eq1);
  step(251, xq2, eq2);
  step(252, xq3, eq3);
  float2 xA=ldx(254), xB=ldx(255);
  float  eA=lde(253), eB=lde(254), eC=lde(255);
  step(253, xA, eA);
  step(254, xB, eB);
  step(255, xB, eC);   // ae(t+1) discarded
}

// ================= K2-gen: lane-per-item generator + GLL (524288 items) =================
__global__ __attribute__((amdgpu_flat_work_group_size(256, 256), amdgpu_waves_per_eu(1, 1)))
void k2_gen(P34 prm)
{
  const int i = blockIdx.x*256 + threadIdx.x;     // = t*BATCH + b
  float* __restrict__ ws = prm.ws;
  const float* __restrict__ seq = prm.p[0];
  float* __restrict__ out = prm.out;

  float w1[100], b1[10], w2[100], b2[10], wm[20], bm[2], wsg[20], bs[2];
  #pragma unroll
  for (int k=0;k<100;k++) w1[k] = prm.p[26][k];
  #pragma unroll
  for (int k=0;k<10;k++)  b1[k] = prm.p[27][k];
  #pragma unroll
  for (int k=0;k<100;k++) w2[k] = prm.p[28][k];
  #pragma unroll
  for (int k=0;k<10;k++)  b2[k] = prm.p[29][k];
  #pragma unroll
  for (int k=0;k<20;k++)  wm[k] = prm.p[30][k];
  #pragma unroll
  for (int k=0;k<2;k++)   bm[k] = prm.p[31][k];
  #pragma unroll
  for (int k=0;k<20;k++)  wsg[k]= prm.p[32][k];
  #pragma unroll
  for (int k=0;k<2;k++)   bs[k] = prm.p[33][k];

  const float* zp = ws + ZOFF + i*10;
  float z[10];
  #pragma unroll
  for (int k=0;k<5;k++){ float2 v = *reinterpret_cast<const float2*>(zp + 2*k); z[2*k]=v.x; z[2*k+1]=v.y; }

  float h1[10];
  #pragma unroll
  for (int o=0;o<10;o++){
    float a = b1[o];
    #pragma unroll
    for (int k=0;k<10;k++) a = fmaf(z[k], w1[k*10+o], a);
    h1[o] = fmaxf(a, 0.f);
  }
  float h2[10];
  #pragma unroll
  for (int o=0;o<10;o++){
    float a = b2[o];
    #pragma unroll
    for (int k=0;k<10;k++) a = fmaf(h1[k], w2[k*10+o], a);
    h2[o] = fmaxf(a, 0.f);
  }
  float m0,m1,s0,s1;
  {
    float am0=bm[0], am1=bm[1], as0=bs[0], as1=bs[1];
    #pragma unroll
    for (int k=0;k<10;k++){
      am0 = fmaf(h2[k], wm[k*2+0], am0);
      am1 = fmaf(h2[k], wm[k*2+1], am1);
      as0 = fmaf(h2[k], wsg[k*2+0], as0);
      as1 = fmaf(h2[k], wsg[k*2+1], as1);
    }
    m0=fsigmU(am0); m1=fsigmU(am1); s0=fsigmU(as0); s1=fsigmU(as1);
  }
  float2 xv = *reinterpret_cast<const float2*>(seq + i*2);
  float d0 = xv.x - m0, d1 = xv.y - m1;
  float ll = __logf(s0) + __logf(s1) + d0*d0*frcp(s0) + d1*d1*frcp(s1);
  float2 mo; mo.x = m0; mo.y = m1;
  *reinterpret_cast<float2*>(out + i*2) = mo;
  ws[LLOFF + i] = -0.5f*ll;
}

// ================= K2-kl: lane-per-item transition + KLD (522240 items, t=1..255) ============
__global__ __attribute__((amdgpu_flat_work_group_size(256, 256), amdgpu_waves_per_eu(1, 1)))
void k2_kl(P34 prm)
{
  const int i = blockIdx.x*256 + threadIdx.x;     // 0..522239
  const int t = 1 + (i >> 11);
  const int b = i & (BATCH-1);
  float* __restrict__ ws = prm.ws;

  float wh[100], bh[10], wmu[100], bmu[10], wsg[100], bsg[10];
  #pragma unroll
  for (int k=0;k<100;k++) wh[k]  = prm.p[20][k];
  #pragma unroll
  for (int k=0;k<10;k++)  bh[k]  = prm.p[21][k];
  #pragma unroll
  for (int k=0;k<100;k++) wmu[k] = prm.p[22][k];
  #pragma unroll
  for (int k=0;k<10;k++)  bmu[k] = prm.p[23][k];
  #pragma unroll
  for (int k=0;k<100;k++) wsg[k] = prm.p[24][k];
  #pragma unroll
  for (int k=0;k<10;k++)  bsg[k] = prm.p[25][k];

  const float* zp  = ws + ZOFF   + ((t-1)*BATCH + b)*10;
  const float* qmp = ws + QMUOFF + (t*BATCH + b)*10;
  const float* qsp = ws + QSGOFF + (t*BATCH + b)*10;
  float z[10], qmu[10], qsg[10];
  #pragma unroll
  for (int k=0;k<5;k++){
    float2 v;
    v = *reinterpret_cast<const float2*>(zp  + 2*k); z[2*k]=v.x;   z[2*k+1]=v.y;
    v = *reinterpret_cast<const float2*>(qmp + 2*k); qmu[2*k]=v.x; qmu[2*k+1]=v.y;
    v = *reinterpret_cast<const float2*>(qsp + 2*k); qsg[2*k]=v.x; qsg[2*k+1]=v.y;
  }

  float th[10];
  #pragma unroll
  for (int o=0;o<10;o++){
    float a = bh[o];
    #pragma unroll
    for (int k=0;k<10;k++) a = fmaf(z[k], wh[k*10+o], a);
    th[o] = ftanhU(a);
  }
  float kl = 0.f;
  #pragma unroll
  for (int o=0;o<10;o++){
    float am = bmu[o], as = bsg[o];
    #pragma unroll
    for (int k=0;k<10;k++){
      am = fmaf(th[k], wmu[k*10+o], am);
      as = fmaf(th[k], wsg[k*10+o], as);
    }
    float prmu = ftanhU(am);
    float prsg = ftanhU(as);
    float dmu = prmu - qmu[o];
    float rp  = frcp(prsg);
    kl += __logf(prsg*frcp(qsg[o])) + (qsg[o] + dmu*dmu)*rp;
  }
  ws[KLOFF + t*BATCH + b] = 0.5f*kl;
}

// ================= K3: loss reduction over t =================
__global__ __launch_bounds__(256, 1) void k3_loss(P34 prm)
{
  __shared__ float red[256];
  const int tid = threadIdx.x;
  const int bl  = tid & 63;
  const int q   = tid >> 6;                      // t-quarter
  const int b   = blockIdx.x*64 + bl;            // grid 32 -> 2048
  const float* __restrict__ kl = prm.ws + KLOFF;
  const float* __restrict__ ll = prm.ws + LLOFF;
  float s = 0.f;
  #pragma unroll 4
  for (int tt = 0; tt < 64; ++tt){
    int t = q*64 + tt;
    s += kl[t*BATCH + b] + ll[t*BATCH + b];
  }
  red[tid] = s;
  __syncthreads();
  if (q == 0){
    s = red[bl] + red[bl+64] + red[bl+128] + red[bl+192];
    const float LOGPI = 1.1447298858494002f;
    prm.out[T_STEPS*BATCH*2 + b] = -s*(1.0f/(float)T_STEPS) + 5.0f + LOGPI;
  }
}

extern "C" void kernel_launch(void* const* d_in, const int* in_sizes, int n_in,
                              void* d_out, int out_size, void* d_ws, size_t ws_size,
                              hipStream_t stream) {
  P34 prm;
  for (int i = 0; i < 34; ++i) prm.p[i] = (const float*)d_in[i];
  prm.ws  = (float*)d_ws;      // needs 64 MiB
  prm.out = (float*)d_out;
  hipLaunchKernelGGL(k1_recur, dim3(512),  dim3(64),  0, stream, prm);
  hipLaunchKernelGGL(k2_gen,   dim3(2048), dim3(256), 0, stream, prm);
  hipLaunchKernelGGL(k2_kl,    dim3(2040), dim3(256), 0, stream, prm);
  hipLaunchKernelGGL(k3_loss,  dim3(32),   dim3(256), 0, stream, prm);
}